// Round 4
// baseline (313.643 us; speedup 1.0000x reference)
//
#include <hip/hip_runtime.h>
#include <hip/hip_cooperative_groups.h>
#include <stdint.h>

#define EMPTY_VAL (-100.0f)

// native vector type: __builtin_nontemporal_* rejects HIP_vector_type
typedef float f4 __attribute__((ext_vector_type(4)));

// Geometry: x[B=8, C=8, D=128, H=128, W=128] fp32
constexpr int B = 8, C = 8;
constexpr int VOX     = 128 * 128 * 128;   // voxels per channel
constexpr int CH_VEC4 = VOX / 4;           // 524,288 float4 per channel
constexpr int THREADS = 256;

// CLASS_RELATIONS = {0:[1,2],1:[0,3],2:[4,5],3:[6,7],4:[0,1],5:[2,3],6:[4,5],7:[6,0]}
constexpr int REL0c[8] = {1, 0, 4, 6, 0, 2, 4, 6};
constexpr int REL1c[8] = {2, 3, 5, 7, 1, 3, 5, 0};

// ---------------- fused cooperative kernel ----------------
constexpr int ITERS_F   = 16;                          // float4-groups per thread
constexpr int V4_BLK_F  = THREADS * ITERS_F;           // 4096 float4 = 16384 vox
constexpr int BPB_F     = CH_VEC4 / V4_BLK_F;          // 128 blocks per batch
constexpr int GRID_F    = B * BPB_F;                   // 1024 blocks (4/CU co-resident)

__global__ __launch_bounds__(THREADS, 4) void fused_kernel(
    const float* __restrict__ x, int* __restrict__ flagsE,
    int* __restrict__ flagsN, float* __restrict__ out) {
  const int b     = blockIdx.x / BPB_F;
  const int chunk = blockIdx.x % BPB_F;
  const int tid   = threadIdx.x;
  const size_t vb4 = (size_t)chunk * V4_BLK_F;

  const f4* xb = reinterpret_cast<const f4*>(x) + (size_t)b * C * CH_VEC4;

  __shared__ uint32_t lds_m[V4_BLK_F];  // 16 KiB: per-voxel positivity byte-mask
  uint32_t anyE = 0, anyN = 0;          // bit c

  // Phase 1: stream x once, build masks + flags.
  for (int it = 0; it < ITERS_F; ++it) {
    const size_t i4 = vb4 + (size_t)it * THREADS + tid;
    uint32_t m = 0;
#pragma unroll
    for (int c = 0; c < C; ++c) {
      const f4 v = __builtin_nontemporal_load(xb + ((size_t)c * CH_VEC4 + i4));
      uint32_t pos = (v.x > 0.f ? 0x00000001u : 0u) |
                     (v.y > 0.f ? 0x00000100u : 0u) |
                     (v.z > 0.f ? 0x00010000u : 0u) |
                     (v.w > 0.f ? 0x01000000u : 0u);
      m |= pos << c;
      const bool e0 = (v.x == EMPTY_VAL), e1 = (v.y == EMPTY_VAL);
      const bool e2 = (v.z == EMPTY_VAL), e3 = (v.w == EMPTY_VAL);
      if (e0 | e1 | e2 | e3)             anyE |= (1u << c);
      if ((!e0) | (!e1) | (!e2) | (!e3)) anyN |= (1u << c);
    }
    lds_m[it * THREADS + tid] = m;
  }

  // Block-level flag reduce: wave OR -> LDS -> one atomic pair per block.
#pragma unroll
  for (int o = 32; o > 0; o >>= 1) {
    anyE |= __shfl_xor((int)anyE, o);
    anyN |= __shfl_xor((int)anyN, o);
  }
  __shared__ int sE, sN;
  if (tid == 0) { sE = 0; sN = 0; }
  __syncthreads();
  if ((tid & 63) == 0) {
    if (anyE) atomicOr(&sE, (int)anyE);
    if (anyN) atomicOr(&sN, (int)anyN);
  }
  __syncthreads();
  if (tid == 0) {
    if (sE) atomicOr(&flagsE[b], sE);
    if (sN) atomicOr(&flagsN[b], sN);
  }

  // Grid-wide barrier: all flags final after this.
  cooperative_groups::this_grid().sync();

  // Device-scope loads (bypass L1) — immune to any fence subtlety.
  const int fE = __hip_atomic_load(&flagsE[b], __ATOMIC_RELAXED, __HIP_MEMORY_SCOPE_AGENT);
  const int fN = __hip_atomic_load(&flagsN[b], __ATOMIC_RELAXED, __HIP_MEMORY_SCOPE_AGENT);

  uint32_t relmask[C];
#pragma unroll
  for (int c = 0; c < C; ++c) {
    const bool all_empty = ((fN >> c) & 1) == 0;
    uint32_t rm = 0;
    if (all_empty) {
      if (((fE >> REL0c[c]) & 1) == 0) rm |= 1u << REL0c[c];
      if (((fE >> REL1c[c]) & 1) == 0) rm |= 1u << REL1c[c];
    }
    relmask[c] = rm * 0x01010101u;
  }

  // Phase 2: emit output from LDS-held masks.
  f4* ob = reinterpret_cast<f4*>(out) + (size_t)b * C * CH_VEC4;
  for (int it = 0; it < ITERS_F; ++it) {
    const size_t i4 = vb4 + (size_t)it * THREADS + tid;
    const uint32_t m = lds_m[it * THREADS + tid];
#pragma unroll
    for (int c = 0; c < C; ++c) {
      const uint32_t t = m & relmask[c];
      f4 r;
      r.x = (t & 0x000000ffu) ? 0.f : EMPTY_VAL;
      r.y = (t & 0x0000ff00u) ? 0.f : EMPTY_VAL;
      r.z = (t & 0x00ff0000u) ? 0.f : EMPTY_VAL;
      r.w = (t & 0xff000000u) ? 0.f : EMPTY_VAL;
      __builtin_nontemporal_store(r, ob + ((size_t)c * CH_VEC4 + i4));
    }
  }
}

// ---------------- fallback: proven R3 two-kernel path ----------------
constexpr int ITERS    = 8;
constexpr int V4_PER_BLOCK     = THREADS * ITERS;        // 2048
constexpr int BLOCKS_PER_BATCH = CH_VEC4 / V4_PER_BLOCK; // 256
constexpr int GRID     = B * BLOCKS_PER_BATCH;           // 2048

__global__ __launch_bounds__(THREADS) void mask_kernel(
    const float* __restrict__ x, uint32_t* __restrict__ mask,
    int* __restrict__ flagsE, int* __restrict__ flagsN) {
  const int b     = blockIdx.x / BLOCKS_PER_BATCH;
  const int chunk = blockIdx.x % BLOCKS_PER_BATCH;
  const int tid   = threadIdx.x;
  const size_t vb4 = (size_t)chunk * V4_PER_BLOCK;

  const f4* xb = reinterpret_cast<const f4*>(x) + (size_t)b * C * CH_VEC4;
  uint32_t* mb = mask + (size_t)b * CH_VEC4;

  uint32_t anyE = 0, anyN = 0;
  for (int it = 0; it < ITERS; ++it) {
    const size_t i4 = vb4 + (size_t)it * THREADS + tid;
    uint32_t m = 0;
#pragma unroll
    for (int c = 0; c < C; ++c) {
      const f4 v = __builtin_nontemporal_load(xb + ((size_t)c * CH_VEC4 + i4));
      uint32_t pos = (v.x > 0.f ? 0x00000001u : 0u) |
                     (v.y > 0.f ? 0x00000100u : 0u) |
                     (v.z > 0.f ? 0x00010000u : 0u) |
                     (v.w > 0.f ? 0x01000000u : 0u);
      m |= pos << c;
      const bool e0 = (v.x == EMPTY_VAL), e1 = (v.y == EMPTY_VAL);
      const bool e2 = (v.z == EMPTY_VAL), e3 = (v.w == EMPTY_VAL);
      if (e0 | e1 | e2 | e3)             anyE |= (1u << c);
      if ((!e0) | (!e1) | (!e2) | (!e3)) anyN |= (1u << c);
    }
    __builtin_nontemporal_store(m, mb + i4);
  }
#pragma unroll
  for (int o = 32; o > 0; o >>= 1) {
    anyE |= __shfl_xor((int)anyE, o);
    anyN |= __shfl_xor((int)anyN, o);
  }
  __shared__ int sE, sN;
  if (tid == 0) { sE = 0; sN = 0; }
  __syncthreads();
  if ((tid & 63) == 0) {
    if (anyE) atomicOr(&sE, (int)anyE);
    if (anyN) atomicOr(&sN, (int)anyN);
  }
  __syncthreads();
  if (tid == 0) {
    if (sE) atomicOr(&flagsE[b], sE);
    if (sN) atomicOr(&flagsN[b], sN);
  }
}

__global__ __launch_bounds__(THREADS) void emit_kernel(
    const uint32_t* __restrict__ mask, const int* __restrict__ flagsE,
    const int* __restrict__ flagsN, float* __restrict__ out) {
  const int b     = blockIdx.x / BLOCKS_PER_BATCH;
  const int chunk = blockIdx.x % BLOCKS_PER_BATCH;
  const int tid   = threadIdx.x;

  const int fE = flagsE[b], fN = flagsN[b];
  uint32_t relmask[C];
#pragma unroll
  for (int c = 0; c < C; ++c) {
    const bool all_empty = ((fN >> c) & 1) == 0;
    uint32_t rm = 0;
    if (all_empty) {
      if (((fE >> REL0c[c]) & 1) == 0) rm |= 1u << REL0c[c];
      if (((fE >> REL1c[c]) & 1) == 0) rm |= 1u << REL1c[c];
    }
    relmask[c] = rm * 0x01010101u;
  }

  const size_t vb4 = (size_t)chunk * V4_PER_BLOCK;
  const uint32_t* mb = mask + (size_t)b * CH_VEC4;
  f4* ob = reinterpret_cast<f4*>(out) + (size_t)b * C * CH_VEC4;

  for (int it = 0; it < ITERS; ++it) {
    const size_t i4 = vb4 + (size_t)it * THREADS + tid;
    const uint32_t m = mb[i4];
#pragma unroll
    for (int c = 0; c < C; ++c) {
      const uint32_t t = m & relmask[c];
      f4 r;
      r.x = (t & 0x000000ffu) ? 0.f : EMPTY_VAL;
      r.y = (t & 0x0000ff00u) ? 0.f : EMPTY_VAL;
      r.z = (t & 0x00ff0000u) ? 0.f : EMPTY_VAL;
      r.w = (t & 0xff000000u) ? 0.f : EMPTY_VAL;
      __builtin_nontemporal_store(r, ob + ((size_t)c * CH_VEC4 + i4));
    }
  }
}

extern "C" void kernel_launch(void* const* d_in, const int* in_sizes, int n_in,
                              void* d_out, int out_size, void* d_ws, size_t ws_size,
                              hipStream_t stream) {
  const float* x = (const float*)d_in[0];
  float* out     = (float*)d_out;

  const size_t mask_bytes = (size_t)B * CH_VEC4 * sizeof(uint32_t);  // 16 MiB
  uint32_t* mask = (uint32_t*)d_ws;
  int* flagsE    = (int*)((char*)d_ws + mask_bytes);
  int* flagsN    = flagsE + 8;

  (void)hipMemsetAsync(flagsE, 0, 16 * sizeof(int), stream);

  // Fused cooperative path (mask never touches HBM).
  void* args[] = {(void*)&x, (void*)&flagsE, (void*)&flagsN, (void*)&out};
  hipError_t err = hipLaunchCooperativeKernel(
      (const void*)fused_kernel, dim3(GRID_F), dim3(THREADS), args, 0, stream);
  if (err == hipSuccess) return;

  // Fallback: proven two-kernel path.
  mask_kernel<<<GRID, THREADS, 0, stream>>>(x, mask, flagsE, flagsN);
  emit_kernel<<<GRID, THREADS, 0, stream>>>(mask, flagsE, flagsN, out);
}

// Round 5
// 205.137 us; speedup vs baseline: 1.5289x; 1.5289x over previous
//
#include <hip/hip_runtime.h>
#include <stdint.h>

#define EMPTY_VAL (-100.0f)

// native vector type: __builtin_nontemporal_* rejects HIP_vector_type
typedef float f4 __attribute__((ext_vector_type(4)));

// Geometry: x[B=8, C=8, D=128, H=128, W=128] fp32
constexpr int B = 8, C = 8;
constexpr int VOX     = 128 * 128 * 128;   // voxels per channel
constexpr int CH_VEC4 = VOX / 4;           // 524,288 float4 per channel
constexpr int THREADS = 256;
constexpr int ITERS   = 8;                              // f4-groups per thread
constexpr int V4_PER_BLOCK = THREADS * ITERS;           // 2048 f4 = 8192 voxels
constexpr int BPB     = CH_VEC4 / V4_PER_BLOCK;         // 256 blocks per batch
constexpr int GRID    = B * BPB;                        // 2048 blocks

// CLASS_RELATIONS = {0:[1,2],1:[0,3],2:[4,5],3:[6,7],4:[0,1],5:[2,3],6:[4,5],7:[6,0]}
constexpr int REL0c[8] = {1, 0, 4, 6, 0, 2, 4, 6};
constexpr int REL1c[8] = {2, 3, 5, 7, 1, 3, 5, 0};

// Pass 1: stream x once (NT loads); write per-voxel positivity byte-mask
// (cacheable store -> stays in L2/L3 for pass 2) and per-block flag words
// (unconditional slot write: no memset, no global atomics, poison-safe).
__global__ __launch_bounds__(THREADS) void mask_kernel(
    const float* __restrict__ x, uint32_t* __restrict__ mask,
    int* __restrict__ partE, int* __restrict__ partN) {
  const int b     = blockIdx.x / BPB;
  const int chunk = blockIdx.x % BPB;
  const int tid   = threadIdx.x;
  const size_t vb4 = (size_t)chunk * V4_PER_BLOCK;

  const f4* xb = reinterpret_cast<const f4*>(x) + (size_t)b * C * CH_VEC4;
  uint32_t* mb = mask + (size_t)b * CH_VEC4;

  uint32_t anyE = 0, anyN = 0;  // bit c
  for (int it = 0; it < ITERS; ++it) {
    const size_t i4 = vb4 + (size_t)it * THREADS + tid;
    uint32_t m = 0;
#pragma unroll
    for (int c = 0; c < C; ++c) {
      const f4 v = __builtin_nontemporal_load(xb + ((size_t)c * CH_VEC4 + i4));
      uint32_t pos = (v.x > 0.f ? 0x00000001u : 0u) |
                     (v.y > 0.f ? 0x00000100u : 0u) |
                     (v.z > 0.f ? 0x00010000u : 0u) |
                     (v.w > 0.f ? 0x01000000u : 0u);
      m |= pos << c;
      const bool e0 = (v.x == EMPTY_VAL), e1 = (v.y == EMPTY_VAL);
      const bool e2 = (v.z == EMPTY_VAL), e3 = (v.w == EMPTY_VAL);
      if (e0 | e1 | e2 | e3)             anyE |= (1u << c);
      if ((!e0) | (!e1) | (!e2) | (!e3)) anyN |= (1u << c);
    }
    mb[i4] = m;  // cacheable: pass 2 re-reads this from L2/L3
  }

  // wave OR-reduce -> LDS combine -> one plain slot store per block
#pragma unroll
  for (int o = 32; o > 0; o >>= 1) {
    anyE |= __shfl_xor((int)anyE, o);
    anyN |= __shfl_xor((int)anyN, o);
  }
  __shared__ int sE, sN;
  if (tid == 0) { sE = 0; sN = 0; }
  __syncthreads();
  if ((tid & 63) == 0) {
    if (anyE) atomicOr(&sE, (int)anyE);
    if (anyN) atomicOr(&sN, (int)anyN);
  }
  __syncthreads();
  if (tid == 0) {
    partE[blockIdx.x] = sE;   // unconditional: no stale state across replays
    partN[blockIdx.x] = sN;
  }
}

// Pass 2: reduce the batch's 256 flag slots in-block, then emit output.
// c-outer/it-inner: long sequential NT write runs; pure-fill fast path for
// channels with no valid relations (no mask reads at all).
__global__ __launch_bounds__(THREADS) void emit_kernel(
    const uint32_t* __restrict__ mask, const int* __restrict__ partE,
    const int* __restrict__ partN, float* __restrict__ out) {
  const int b     = blockIdx.x / BPB;
  const int chunk = blockIdx.x % BPB;
  const int tid   = threadIdx.x;

  // flag reduce: 256 threads each load one slot pair (L2-broadcast), OR-reduce
  int e = partE[b * BPB + tid];
  int n = partN[b * BPB + tid];
#pragma unroll
  for (int o = 32; o > 0; o >>= 1) {
    e |= __shfl_xor(e, o);
    n |= __shfl_xor(n, o);
  }
  __shared__ int sE, sN;
  if (tid == 0) { sE = 0; sN = 0; }
  __syncthreads();
  if ((tid & 63) == 0) {
    if (e) atomicOr(&sE, e);
    if (n) atomicOr(&sN, n);
  }
  __syncthreads();
  const int fE = sE, fN = sN;

  const size_t vb4 = (size_t)chunk * V4_PER_BLOCK;
  const uint32_t* mb = mask + (size_t)b * CH_VEC4;
  f4* ob = reinterpret_cast<f4*>(out) + (size_t)b * C * CH_VEC4;

  const f4 empty4 = {EMPTY_VAL, EMPTY_VAL, EMPTY_VAL, EMPTY_VAL};

#pragma unroll
  for (int c = 0; c < C; ++c) {
    const bool all_empty = ((fN >> c) & 1) == 0;
    uint32_t rm = 0;
    if (all_empty) {
      if (((fE >> REL0c[c]) & 1) == 0) rm |= 1u << REL0c[c];
      if (((fE >> REL1c[c]) & 1) == 0) rm |= 1u << REL1c[c];
    }
    const uint32_t relmask = rm * 0x01010101u;
    f4* oc = ob + (size_t)c * CH_VEC4;

    if (relmask == 0u) {          // block-uniform: pure EMPTY fill, no mask reads
      for (int it = 0; it < ITERS; ++it) {
        const size_t i4 = vb4 + (size_t)it * THREADS + tid;
        __builtin_nontemporal_store(empty4, oc + i4);
      }
    } else {
      for (int it = 0; it < ITERS; ++it) {
        const size_t i4 = vb4 + (size_t)it * THREADS + tid;
        const uint32_t t = mb[i4] & relmask;  // L1-hit after first such c
        f4 r;
        r.x = (t & 0x000000ffu) ? 0.f : EMPTY_VAL;
        r.y = (t & 0x0000ff00u) ? 0.f : EMPTY_VAL;
        r.z = (t & 0x00ff0000u) ? 0.f : EMPTY_VAL;
        r.w = (t & 0xff000000u) ? 0.f : EMPTY_VAL;
        __builtin_nontemporal_store(r, oc + i4);
      }
    }
  }
}

extern "C" void kernel_launch(void* const* d_in, const int* in_sizes, int n_in,
                              void* d_out, int out_size, void* d_ws, size_t ws_size,
                              hipStream_t stream) {
  const float* x = (const float*)d_in[0];
  float* out     = (float*)d_out;

  const size_t mask_bytes = (size_t)B * CH_VEC4 * sizeof(uint32_t);  // 16 MiB
  uint32_t* mask = (uint32_t*)d_ws;
  int* partE     = (int*)((char*)d_ws + mask_bytes);
  int* partN     = partE + GRID;

  mask_kernel<<<GRID, THREADS, 0, stream>>>(x, mask, partE, partN);
  emit_kernel<<<GRID, THREADS, 0, stream>>>(mask, partE, partN, out);
}

// Round 6
// 198.641 us; speedup vs baseline: 1.5789x; 1.0327x over previous
//
#include <hip/hip_runtime.h>
#include <stdint.h>

#define EMPTY_VAL (-100.0f)

// native vector type: __builtin_nontemporal_* rejects HIP_vector_type
typedef float f4 __attribute__((ext_vector_type(4)));

// Geometry: x[B=8, C=8, D=128, H=128, W=128] fp32
constexpr int B = 8, C = 8;
constexpr int VOX     = 128 * 128 * 128;   // voxels per channel
constexpr int CH_VEC4 = VOX / 4;           // 524,288 float4 per channel
constexpr int THREADS = 256;
constexpr int ITERS   = 8;                              // f4-groups per thread
constexpr int V4_PER_BLOCK = THREADS * ITERS;           // 2048 f4 = 8192 voxels
constexpr int BPB     = CH_VEC4 / V4_PER_BLOCK;         // 256 blocks per batch
constexpr int GRID    = B * BPB;                        // 2048 blocks

// CLASS_RELATIONS = {0:[1,2],1:[0,3],2:[4,5],3:[6,7],4:[0,1],5:[2,3],6:[4,5],7:[6,0]}
constexpr int REL0c[8] = {1, 0, 4, 6, 0, 2, 4, 6};
constexpr int REL1c[8] = {2, 3, 5, 7, 1, 3, 5, 0};

// Pass 1: stream x once (NT loads); write per-voxel positivity byte-mask
// (cacheable store -> stays in L2/L3 for pass 2) and per-block flag words
// (unconditional slot write: no memset, no global atomics, poison-safe).
__global__ __launch_bounds__(THREADS) void mask_kernel(
    const float* __restrict__ x, uint32_t* __restrict__ mask,
    int* __restrict__ partE, int* __restrict__ partN) {
  const int b     = blockIdx.x / BPB;
  const int chunk = blockIdx.x % BPB;
  const int tid   = threadIdx.x;
  const size_t vb4 = (size_t)chunk * V4_PER_BLOCK;

  const f4* xb = reinterpret_cast<const f4*>(x) + (size_t)b * C * CH_VEC4;
  uint32_t* mb = mask + (size_t)b * CH_VEC4;

  uint32_t anyE = 0, anyN = 0;  // bit c
#pragma unroll
  for (int it = 0; it < ITERS; ++it) {
    const size_t i4 = vb4 + (size_t)it * THREADS + tid;
    uint32_t m = 0;
#pragma unroll
    for (int c = 0; c < C; ++c) {
      const f4 v = __builtin_nontemporal_load(xb + ((size_t)c * CH_VEC4 + i4));
      uint32_t pos = (v.x > 0.f ? 0x00000001u : 0u) |
                     (v.y > 0.f ? 0x00000100u : 0u) |
                     (v.z > 0.f ? 0x00010000u : 0u) |
                     (v.w > 0.f ? 0x01000000u : 0u);
      m |= pos << c;
      const bool e0 = (v.x == EMPTY_VAL), e1 = (v.y == EMPTY_VAL);
      const bool e2 = (v.z == EMPTY_VAL), e3 = (v.w == EMPTY_VAL);
      if (e0 | e1 | e2 | e3)             anyE |= (1u << c);
      if ((!e0) | (!e1) | (!e2) | (!e3)) anyN |= (1u << c);
    }
    mb[i4] = m;  // cacheable: pass 2 re-reads this from L2/L3
  }

  // wave OR-reduce -> LDS combine -> one plain slot store per block
#pragma unroll
  for (int o = 32; o > 0; o >>= 1) {
    anyE |= __shfl_xor((int)anyE, o);
    anyN |= __shfl_xor((int)anyN, o);
  }
  __shared__ int sE, sN;
  if (tid == 0) { sE = 0; sN = 0; }
  __syncthreads();
  if ((tid & 63) == 0) {
    if (anyE) atomicOr(&sE, (int)anyE);
    if (anyN) atomicOr(&sN, (int)anyN);
  }
  __syncthreads();
  if (tid == 0) {
    partE[blockIdx.x] = sE;   // unconditional: no stale state across replays
    partN[blockIdx.x] = sN;
  }
}

// Pass 2: reduce the batch's 256 flag slots in-block, then emit output.
// Fill channels first (c-outer: long sequential NT write runs, no mask reads);
// then mask-dependent channels it-outer/c-inner so each mask word is loaded
// once per iteration and reused across channels.
__global__ __launch_bounds__(THREADS) void emit_kernel(
    const uint32_t* __restrict__ mask, const int* __restrict__ partE,
    const int* __restrict__ partN, float* __restrict__ out) {
  const int b     = blockIdx.x / BPB;
  const int chunk = blockIdx.x % BPB;
  const int tid   = threadIdx.x;

  // flag reduce: 256 threads each load one slot pair (L2/L3 broadcast), OR-reduce
  int e = partE[b * BPB + tid];
  int n = partN[b * BPB + tid];
#pragma unroll
  for (int o = 32; o > 0; o >>= 1) {
    e |= __shfl_xor(e, o);
    n |= __shfl_xor(n, o);
  }
  __shared__ int sE, sN;
  if (tid == 0) { sE = 0; sN = 0; }
  __syncthreads();
  if ((tid & 63) == 0) {
    if (e) atomicOr(&sE, e);
    if (n) atomicOr(&sN, n);
  }
  __syncthreads();
  const int fE = sE, fN = sN;

  // classify channels (block-uniform)
  uint32_t rmv[C];
  bool any_masked = false;
#pragma unroll
  for (int c = 0; c < C; ++c) {
    const bool all_empty = ((fN >> c) & 1) == 0;
    uint32_t rm = 0;
    if (all_empty) {
      if (((fE >> REL0c[c]) & 1) == 0) rm |= 1u << REL0c[c];
      if (((fE >> REL1c[c]) & 1) == 0) rm |= 1u << REL1c[c];
    }
    rmv[c] = rm * 0x01010101u;
    any_masked |= (rm != 0);
  }

  const size_t vb4 = (size_t)chunk * V4_PER_BLOCK;
  const uint32_t* mb = mask + (size_t)b * CH_VEC4;
  f4* ob = reinterpret_cast<f4*>(out) + (size_t)b * C * CH_VEC4;

  const f4 empty4 = {EMPTY_VAL, EMPTY_VAL, EMPTY_VAL, EMPTY_VAL};

  // 1) pure-fill channels: c-outer, long store runs, zero reads
#pragma unroll
  for (int c = 0; c < C; ++c) {
    if (rmv[c] == 0u) {
      f4* oc = ob + (size_t)c * CH_VEC4;
#pragma unroll
      for (int it = 0; it < ITERS; ++it) {
        const size_t i4 = vb4 + (size_t)it * THREADS + tid;
        __builtin_nontemporal_store(empty4, oc + i4);
      }
    }
  }

  // 2) mask-dependent channels: it-outer, one mask load reused across channels
  if (any_masked) {
    for (int it = 0; it < ITERS; ++it) {
      const size_t i4 = vb4 + (size_t)it * THREADS + tid;
      const uint32_t m = mb[i4];
#pragma unroll
      for (int c = 0; c < C; ++c) {
        if (rmv[c] != 0u) {
          const uint32_t t = m & rmv[c];
          f4 r;
          r.x = (t & 0x000000ffu) ? 0.f : EMPTY_VAL;
          r.y = (t & 0x0000ff00u) ? 0.f : EMPTY_VAL;
          r.z = (t & 0x00ff0000u) ? 0.f : EMPTY_VAL;
          r.w = (t & 0xff000000u) ? 0.f : EMPTY_VAL;
          __builtin_nontemporal_store(r, ob + ((size_t)c * CH_VEC4 + i4));
        }
      }
    }
  }
}

extern "C" void kernel_launch(void* const* d_in, const int* in_sizes, int n_in,
                              void* d_out, int out_size, void* d_ws, size_t ws_size,
                              hipStream_t stream) {
  const float* x = (const float*)d_in[0];
  float* out     = (float*)d_out;

  const size_t mask_bytes = (size_t)B * CH_VEC4 * sizeof(uint32_t);  // 16 MiB
  uint32_t* mask = (uint32_t*)d_ws;
  int* partE     = (int*)((char*)d_ws + mask_bytes);
  int* partN     = partE + GRID;

  mask_kernel<<<GRID, THREADS, 0, stream>>>(x, mask, partE, partN);
  emit_kernel<<<GRID, THREADS, 0, stream>>>(mask, partE, partN, out);
}